// Round 1
// baseline (2828.555 us; speedup 1.0000x reference)
//
#include <hip/hip_runtime.h>

#define EPS 1e-5f

__device__ __forceinline__ float wred(float v){
#pragma unroll
  for(int m=32;m>=1;m>>=1) v += __shfl_xor(v,m,64);
  return v;
}

__device__ __forceinline__ unsigned short f2bf(float f){
  union{unsigned int i; float x;}v; v.x=f;
  unsigned int u=v.i;
  unsigned int r=(u + 0x7fffu + ((u>>16)&1u))>>16;
  return (unsigned short)r;
}
__device__ __forceinline__ float bflo(unsigned int u){
  union{unsigned int i; float x;}v; v.i=u<<16; return v.x;
}
__device__ __forceinline__ float bfhi(unsigned int u){
  union{unsigned int i; float x;}v; v.i=u&0xffff0000u; return v.x;
}

// ---------------- kT: transpose W2 weights so inner dot loops are contiguous (s_load_dwordx batches)
__global__ __launch_bounds__(256) void kT(const float* __restrict__ kW2, const float* __restrict__ qW2,
                                          const float* __restrict__ vW2, const float* __restrict__ dW2,
                                          float* __restrict__ pW){
  for(int idx=threadIdx.x; idx<2048; idx+=256){
    int i=idx>>6, j=idx&63;            // W2 is [32][64]
    pW[j*32+i]       = kW2[idx];
    pW[2048+j*32+i]  = qW2[idx];
    pW[4096+j*32+i]  = vW2[idx];
  }
  for(int idx=threadIdx.x; idx<512; idx+=256){
    int i=idx>>4, j=idx&15;            // dW2 is [32][16]
    pW[6144+j*32+i]  = dW2[idx];
  }
}

// ---------------- kA: input moments (63 accumulators), block partials [63][1024]
__global__ __launch_bounds__(256) void kA(const float* __restrict__ rot, const float* __restrict__ tra,
                                          float* __restrict__ pA, int N){
  float a[63];
#pragma unroll
  for(int i=0;i<63;i++) a[i]=0.f;
  int stride = gridDim.x*blockDim.x;
  for(int row=blockIdx.x*blockDim.x+threadIdx.x; row<N; row+=stride){
    float t[3], r[9];
#pragma unroll
    for(int i=0;i<3;i++) t[i]=tra[row*3+i];
#pragma unroll
    for(int i=0;i<9;i++) r[i]=rot[row*9+i];
#pragma unroll
    for(int i=0;i<3;i++) a[i]+=t[i];
#pragma unroll
    for(int i=0;i<3;i++)
#pragma unroll
      for(int j=i;j<3;j++) a[3 + i*3 - (i*(i-1))/2 + (j-i)] += t[i]*t[j];
#pragma unroll
    for(int i=0;i<9;i++) a[9+i]+=r[i];
#pragma unroll
    for(int i=0;i<9;i++)
#pragma unroll
      for(int j=i;j<9;j++) a[18 + i*9 - (i*(i-1))/2 + (j-i)] += r[i]*r[j];
  }
#pragma unroll
  for(int i=0;i<63;i++) a[i]=wred(a[i]);
  __shared__ float lds[4][63];
  int wave=threadIdx.x>>6, lane=threadIdx.x&63;
  if(lane==0){
#pragma unroll
    for(int i=0;i<63;i++) lds[wave][i]=a[i];
  }
  __syncthreads();
  int t=threadIdx.x;
  if(t<63) pA[t*gridDim.x + blockIdx.x] = lds[0][t]+lds[1][t]+lds[2][t]+lds[3][t];
}

// ---------------- kA2: reduce moment partials, compute folded BN1 scale/bias for k/q/v
__global__ __launch_bounds__(256) void kA2(const float* __restrict__ pA, int nb,
    const float* __restrict__ kW1, const float* __restrict__ kg, const float* __restrict__ kb,
    const float* __restrict__ qW1, const float* __restrict__ qg, const float* __restrict__ qb,
    const float* __restrict__ vW1, const float* __restrict__ vg, const float* __restrict__ vb,
    float* __restrict__ cst, float invN){
  __shared__ float tmp[63][4];
  __shared__ float mom[63];
  int t=threadIdx.x;
  if(t<252){
    int f=t>>2, q=t&3;
    int per=nb/4;
    float s=0.f;
    for(int i=0;i<per;i++) s+=pA[f*nb + q*per + i];
    tmp[f][q]=s;
  }
  __syncthreads();
  if(t<63) mom[t]=tmp[t][0]+tmp[t][1]+tmp[t][2]+tmp[t][3];
  __syncthreads();
  if(t<96){
    int net=t>>5, j=t&31;
    const float* W1; const float* g; const float* b; int din, sbase, mbase, obase;
    if(net==0){W1=kW1;g=kg;b=kb;din=3;sbase=0;mbase=3;obase=0;}
    else if(net==1){W1=qW1;g=qg;b=qb;din=9;sbase=9;mbase=18;obase=64;}
    else {W1=vW1;g=vg;b=vb;din=3;sbase=0;mbase=3;obase=128;}
    float mean=0.f, ex2=0.f;
    for(int i=0;i<din;i++){
      float wi=W1[i*32+j];
      mean += mom[sbase+i]*wi;
      int rowb = mbase + i*din - (i*(i-1))/2;
      for(int i2=i;i2<din;i2++){
        float w2=W1[i2*32+j];
        float m=mom[rowb + (i2-i)];
        ex2 += ((i2==i)?1.f:2.f)*wi*w2*m;
      }
    }
    mean*=invN; ex2*=invN;
    float var=ex2-mean*mean;
    float sc=g[j]*rsqrtf(var+EPS);
    float bi=b[j]-mean*sc;
    cst[obase+j]=sc; cst[obase+32+j]=bi;
  }
}

// ---------------- kRed: reduce per-block {sum,sumsq} partials -> BN scale/bias
__global__ __launch_bounds__(256) void kRed(const float* __restrict__ part, int nf, int nb,
    const float* __restrict__ g, const float* __restrict__ b, float* __restrict__ cstOut, float invN){
  int f=blockIdx.x;
  float s1=0.f,s2=0.f;
  for(int i=threadIdx.x;i<nb;i+=256){ s1+=part[f*nb+i]; s2+=part[(nf+f)*nb+i]; }
  s1=wred(s1); s2=wred(s2);
  __shared__ float l1[4],l2[4];
  int wave=threadIdx.x>>6;
  if((threadIdx.x&63)==0){l1[wave]=s1;l2[wave]=s2;}
  __syncthreads();
  if(threadIdx.x==0){
    float a=l1[0]+l1[1]+l1[2]+l1[3];
    float c=l2[0]+l2[1]+l2[2]+l2[3];
    float mean=a*invN;
    float var=c*invN-mean*mean;
    float sc=g[f]*rsqrtf(var+EPS);
    float bi=b[f]-mean*sc;
    cstOut[f]=sc; cstOut[nf+f]=bi;
  }
}

// ---------------- kHeavy: per-row pipeline. TAIL=0: y1 (+store,+stats). TAIL=1: ->y2 stats. TAIL=2: ->out.
template<int TAIL, int STORE>
__global__ __launch_bounds__(256) void kHeavy(
    const float* __restrict__ rot, const float* __restrict__ tra,
    const float* __restrict__ kW1, const float* __restrict__ qW1, const float* __restrict__ vW1,
    const float* __restrict__ kb2, const float* __restrict__ qb2, const float* __restrict__ vb2,
    const float* __restrict__ W2T, const float* __restrict__ dW1,
    const float* __restrict__ dW3, const float* __restrict__ db3,
    const float* __restrict__ cst,
    unsigned short* __restrict__ y1o, float* __restrict__ pOut, float* __restrict__ outp, int N)
{
  const float* kW2T=W2T;
  const float* qW2T=W2T+2048;
  const float* vW2T=W2T+4096;
  const float* dW2T=W2T+6144;
  int row=blockIdx.x*256+threadIdx.x;
  bool valid=row<N;
  int lrow=valid?row:0;
  float t0=tra[lrow*3+0], t1=tra[lrow*3+1], t2=tra[lrow*3+2];
  float r[9];
#pragma unroll
  for(int i=0;i<9;i++) r[i]=rot[lrow*9+i];
  float hk[32],hq[32];
#pragma unroll
  for(int j=0;j<32;j++){
    float x=t0*kW1[j]+t1*kW1[32+j]+t2*kW1[64+j];
    x=x*cst[j]+cst[32+j];
    hk[j]=x>0.f?x:0.f;
  }
#pragma unroll
  for(int j=0;j<32;j++){
    float x=0.f;
#pragma unroll
    for(int i=0;i<9;i++) x+=r[i]*qW1[i*32+j];
    x=x*cst[64+j]+cst[96+j];
    hq[j]=x>0.f?x:0.f;
  }
  float s[64];
#pragma unroll
  for(int j=0;j<64;j++){
    float kj=kb2[j], qj=qb2[j];
#pragma unroll
    for(int i=0;i<32;i++){
      kj+=hk[i]*kW2T[j*32+i];
      qj+=hq[i]*qW2T[j*32+i];
    }
    s[j]=kj*qj;
  }
  float mx=s[0];
#pragma unroll
  for(int j=1;j<64;j++) mx=fmaxf(mx,s[j]);
  float Z=0.f;
#pragma unroll
  for(int j=0;j<64;j++){ float e=__expf(s[j]-mx); s[j]=e; Z+=e; }
  float inv=1.f/Z;
  float hv[32];
#pragma unroll
  for(int j=0;j<32;j++){
    float x=t0*vW1[j]+t1*vW1[32+j]+t2*vW1[64+j];
    x=x*cst[128+j]+cst[160+j];
    hv[j]=x>0.f?x:0.f;
  }
  float y1[32];
#pragma unroll
  for(int i=0;i<32;i++) y1[i]=0.f;
#pragma unroll
  for(int j=0;j<64;j++){
    float vj=vb2[j];
#pragma unroll
    for(int i=0;i<32;i++) vj+=hv[i]*vW2T[j*32+i];
    float a=s[j]*inv*vj;
#pragma unroll
    for(int i=0;i<32;i++) y1[i]+=a*dW1[j*32+i];
  }
  if(!valid){
#pragma unroll
    for(int i=0;i<32;i++) y1[i]=0.f;
  }
  if constexpr (TAIL==0){
    if constexpr (STORE){
      if(valid){
        unsigned int w[16];
#pragma unroll
        for(int kk=0;kk<16;kk++) w[kk]=(unsigned int)f2bf(y1[2*kk])|((unsigned int)f2bf(y1[2*kk+1])<<16);
        uint4* dst=(uint4*)(y1o+(size_t)row*32);
        dst[0]=make_uint4(w[0],w[1],w[2],w[3]);
        dst[1]=make_uint4(w[4],w[5],w[6],w[7]);
        dst[2]=make_uint4(w[8],w[9],w[10],w[11]);
        dst[3]=make_uint4(w[12],w[13],w[14],w[15]);
      }
    }
    __shared__ float lS[4][32], lQ[4][32];
    int wave=threadIdx.x>>6, lane=threadIdx.x&63;
#pragma unroll
    for(int i=0;i<32;i++){
      float sm=wred(y1[i]);
      float sq=wred(y1[i]*y1[i]);
      if(lane==0){lS[wave][i]=sm;lQ[wave][i]=sq;}
    }
    __syncthreads();
    if(threadIdx.x<32){
      int f=threadIdx.x;
      pOut[f*gridDim.x+blockIdx.x]=lS[0][f]+lS[1][f]+lS[2][f]+lS[3][f];
      pOut[(32+f)*gridDim.x+blockIdx.x]=lQ[0][f]+lQ[1][f]+lQ[2][f]+lQ[3][f];
    }
  } else {
    float h2[32];
#pragma unroll
    for(int i=0;i<32;i++){
      float x=y1[i]*cst[192+i]+cst[224+i];
      h2[i]=x>0.f?x:0.f;
    }
    float y2[16];
#pragma unroll
    for(int j=0;j<16;j++){
      float acc=0.f;
#pragma unroll
      for(int i=0;i<32;i++) acc+=h2[i]*dW2T[j*32+i];
      y2[j]=valid?acc:0.f;
    }
    if constexpr (TAIL==1){
      __shared__ float lS[4][16], lQ[4][16];
      int wave=threadIdx.x>>6, lane=threadIdx.x&63;
#pragma unroll
      for(int i=0;i<16;i++){
        float sm=wred(y2[i]);
        float sq=wred(y2[i]*y2[i]);
        if(lane==0){lS[wave][i]=sm;lQ[wave][i]=sq;}
      }
      __syncthreads();
      if(threadIdx.x<16){
        int f=threadIdx.x;
        pOut[f*gridDim.x+blockIdx.x]=lS[0][f]+lS[1][f]+lS[2][f]+lS[3][f];
        pOut[(16+f)*gridDim.x+blockIdx.x]=lQ[0][f]+lQ[1][f]+lQ[2][f]+lQ[3][f];
      }
    } else {
      if(valid){
        float o=db3[0];
#pragma unroll
        for(int j=0;j<16;j++){
          float x=y2[j]*cst[256+j]+cst[272+j];
          x=x>0.f?x:0.f;
          o+=x*dW3[j];
        }
        outp[row]=1.f/(1.f+__expf(-o));
      }
    }
  }
}

// ---------------- kC: y1(bf16) -> BN-d1 -> ReLU -> dW2 -> y2(bf16) + stats
__global__ __launch_bounds__(256) void kC(const unsigned short* __restrict__ y1,
    const float* __restrict__ cst, const float* __restrict__ dW2T,
    unsigned short* __restrict__ y2, float* __restrict__ pC, int N){
  int row=blockIdx.x*256+threadIdx.x;
  bool valid=row<N;
  int lrow=valid?row:0;
  const uint4* src=(const uint4*)(y1+(size_t)lrow*32);
  uint4 q0=src[0],q1=src[1],q2=src[2],q3=src[3];
  unsigned int w[16]={q0.x,q0.y,q0.z,q0.w,q1.x,q1.y,q1.z,q1.w,
                      q2.x,q2.y,q2.z,q2.w,q3.x,q3.y,q3.z,q3.w};
  float h[32];
#pragma unroll
  for(int kk=0;kk<16;kk++){
    float lo=bflo(w[kk]), hi=bfhi(w[kk]);
    float a=lo*cst[192+2*kk]+cst[224+2*kk];
    float b=hi*cst[192+2*kk+1]+cst[224+2*kk+1];
    h[2*kk]  = a>0.f?a:0.f;
    h[2*kk+1]= b>0.f?b:0.f;
  }
  float y[16];
#pragma unroll
  for(int j=0;j<16;j++){
    float acc=0.f;
#pragma unroll
    for(int i=0;i<32;i++) acc+=h[i]*dW2T[j*32+i];
    y[j]=valid?acc:0.f;
  }
  if(valid){
    unsigned int o[8];
#pragma unroll
    for(int kk=0;kk<8;kk++) o[kk]=(unsigned int)f2bf(y[2*kk])|((unsigned int)f2bf(y[2*kk+1])<<16);
    uint4* dst=(uint4*)(y2+(size_t)row*16);
    dst[0]=make_uint4(o[0],o[1],o[2],o[3]);
    dst[1]=make_uint4(o[4],o[5],o[6],o[7]);
  }
  __shared__ float lS[4][16], lQ[4][16];
  int wave=threadIdx.x>>6, lane=threadIdx.x&63;
#pragma unroll
  for(int i=0;i<16;i++){
    float sm=wred(y[i]);
    float sq=wred(y[i]*y[i]);
    if(lane==0){lS[wave][i]=sm;lQ[wave][i]=sq;}
  }
  __syncthreads();
  if(threadIdx.x<16){
    int f=threadIdx.x;
    pC[f*gridDim.x+blockIdx.x]=lS[0][f]+lS[1][f]+lS[2][f]+lS[3][f];
    pC[(16+f)*gridDim.x+blockIdx.x]=lQ[0][f]+lQ[1][f]+lQ[2][f]+lQ[3][f];
  }
}

// ---------------- kD: y2(bf16) -> BN-d2 -> ReLU -> dW3+db3 -> sigmoid -> out
__global__ __launch_bounds__(256) void kD(const unsigned short* __restrict__ y2,
    const float* __restrict__ cst, const float* __restrict__ dW3, const float* __restrict__ db3,
    float* __restrict__ outp, int N){
  int row=blockIdx.x*256+threadIdx.x;
  if(row>=N) return;
  const uint4* src=(const uint4*)(y2+(size_t)row*16);
  uint4 q0=src[0],q1=src[1];
  unsigned int w[8]={q0.x,q0.y,q0.z,q0.w,q1.x,q1.y,q1.z,q1.w};
  float o=db3[0];
#pragma unroll
  for(int kk=0;kk<8;kk++){
    float lo=bflo(w[kk])*cst[256+2*kk]+cst[272+2*kk];
    float hi=bfhi(w[kk])*cst[256+2*kk+1]+cst[272+2*kk+1];
    lo=lo>0.f?lo:0.f; hi=hi>0.f?hi:0.f;
    o+=lo*dW3[2*kk]+hi*dW3[2*kk+1];
  }
  outp[row]=1.f/(1.f+__expf(-o));
}

extern "C" void kernel_launch(void* const* d_in, const int* in_sizes, int n_in,
                              void* d_out, int out_size, void* d_ws, size_t ws_size,
                              hipStream_t stream){
  const float* rot=(const float*)d_in[0];
  const float* tra=(const float*)d_in[1];
  const float* kW1=(const float*)d_in[2];
  const float* kg =(const float*)d_in[3];
  const float* kb =(const float*)d_in[4];
  const float* kW2=(const float*)d_in[5];
  const float* kb2=(const float*)d_in[6];
  const float* qW1=(const float*)d_in[7];
  const float* qg =(const float*)d_in[8];
  const float* qb =(const float*)d_in[9];
  const float* qW2=(const float*)d_in[10];
  const float* qb2=(const float*)d_in[11];
  const float* vW1=(const float*)d_in[12];
  const float* vg =(const float*)d_in[13];
  const float* vb =(const float*)d_in[14];
  const float* vW2=(const float*)d_in[15];
  const float* vb2=(const float*)d_in[16];
  const float* dW1=(const float*)d_in[17];
  const float* dg1=(const float*)d_in[18];
  const float* db1=(const float*)d_in[19];
  const float* dW2=(const float*)d_in[20];
  const float* dg2=(const float*)d_in[21];
  const float* db2=(const float*)d_in[22];
  const float* dW3=(const float*)d_in[23];
  const float* db3=(const float*)d_in[24];

  int N=in_sizes[0]/9;
  int nb=(N+255)/256;

  float* ws=(float*)d_ws;
  float* cst=ws;                       // 1024 floats (BN consts)
  float* pA =ws+1024;                  // [63][1024]
  float* pB =ws+65536;                 // [64][nb]
  float* pC =pB+(size_t)64*nb;         // [32][nb]
  float* pW =pC+(size_t)32*nb;         // 6656 floats (transposed weights)

  size_t y1off=(size_t)8<<20;          // bytes; partials+consts end well below 8 MiB for nb=8192
  unsigned short* y1=(unsigned short*)((char*)d_ws + y1off);
  unsigned short* y2=(unsigned short*)((char*)d_ws + y1off + (size_t)N*64);
  size_t need=y1off + (size_t)N*64 + (size_t)N*32;
  bool store = ws_size>=need;
  float invN=1.f/(float)N;
  dim3 B(256);

  kT <<<dim3(1),   B,0,stream>>>(kW2,qW2,vW2,dW2,pW);
  kA <<<dim3(1024),B,0,stream>>>(rot,tra,pA,N);
  kA2<<<dim3(1),   B,0,stream>>>(pA,1024,kW1,kg,kb,qW1,qg,qb,vW1,vg,vb,cst,invN);

  if(store){
    kHeavy<0,1><<<dim3(nb),B,0,stream>>>(rot,tra,kW1,qW1,vW1,kb2,qb2,vb2,pW,dW1,dW3,db3,cst,y1,pB,nullptr,N);
    kRed<<<dim3(32),B,0,stream>>>(pB,32,nb,dg1,db1,cst+192,invN);
    kC  <<<dim3(nb),B,0,stream>>>(y1,cst,pW+6144,y2,pC,N);
    kRed<<<dim3(16),B,0,stream>>>(pC,16,nb,dg2,db2,cst+256,invN);
    kD  <<<dim3(nb),B,0,stream>>>(y2,cst,dW3,db3,(float*)d_out,N);
  } else {
    kHeavy<0,0><<<dim3(nb),B,0,stream>>>(rot,tra,kW1,qW1,vW1,kb2,qb2,vb2,pW,dW1,dW3,db3,cst,nullptr,pB,nullptr,N);
    kRed<<<dim3(32),B,0,stream>>>(pB,32,nb,dg1,db1,cst+192,invN);
    kHeavy<1,0><<<dim3(nb),B,0,stream>>>(rot,tra,kW1,qW1,vW1,kb2,qb2,vb2,pW,dW1,dW3,db3,cst,nullptr,pC,nullptr,N);
    kRed<<<dim3(16),B,0,stream>>>(pC,16,nb,dg2,db2,cst+256,invN);
    kHeavy<2,0><<<dim3(nb),B,0,stream>>>(rot,tra,kW1,qW1,vW1,kb2,qb2,vb2,pW,dW1,dW3,db3,cst,nullptr,nullptr,(float*)d_out,N);
  }
}

// Round 2
// 2707.011 us; speedup vs baseline: 1.0449x; 1.0449x over previous
//
#include <hip/hip_runtime.h>

#define EPS 1e-5f

#define REP16(M) M(0) M(1) M(2) M(3) M(4) M(5) M(6) M(7) M(8) M(9) M(10) M(11) M(12) M(13) M(14) M(15)
#define REP64(M) M(0) M(1) M(2) M(3) M(4) M(5) M(6) M(7) M(8) M(9) \
  M(10) M(11) M(12) M(13) M(14) M(15) M(16) M(17) M(18) M(19) \
  M(20) M(21) M(22) M(23) M(24) M(25) M(26) M(27) M(28) M(29) \
  M(30) M(31) M(32) M(33) M(34) M(35) M(36) M(37) M(38) M(39) \
  M(40) M(41) M(42) M(43) M(44) M(45) M(46) M(47) M(48) M(49) \
  M(50) M(51) M(52) M(53) M(54) M(55) M(56) M(57) M(58) M(59) \
  M(60) M(61) M(62) M(63)

__device__ __forceinline__ float wred(float v){
#pragma unroll
  for(int m=32;m>=1;m>>=1) v += __shfl_xor(v,m,64);
  return v;
}

__device__ __forceinline__ unsigned short f2bf(float f){
  union{unsigned int i; float x;}v; v.x=f;
  unsigned int u=v.i;
  unsigned int r=(u + 0x7fffu + ((u>>16)&1u))>>16;
  return (unsigned short)r;
}
__device__ __forceinline__ float bflo(unsigned int u){
  union{unsigned int i; float x;}v; v.i=u<<16; return v.x;
}
__device__ __forceinline__ float bfhi(unsigned int u){
  union{unsigned int i; float x;}v; v.i=u&0xffff0000u; return v.x;
}

// ---------------- kT: transpose W2 weights so inner dot loops are contiguous
__global__ __launch_bounds__(256) void kT(const float* __restrict__ kW2, const float* __restrict__ qW2,
                                          const float* __restrict__ vW2, const float* __restrict__ dW2,
                                          float* __restrict__ pW){
  for(int idx=threadIdx.x; idx<2048; idx+=256){
    int i=idx>>6, j=idx&63;            // W2 is [32][64]
    pW[j*32+i]       = kW2[idx];
    pW[2048+j*32+i]  = qW2[idx];
    pW[4096+j*32+i]  = vW2[idx];
  }
  for(int idx=threadIdx.x; idx<512; idx+=256){
    int i=idx>>4, j=idx&15;            // dW2 is [32][16]
    pW[6144+j*32+i]  = dW2[idx];
  }
}

// ---------------- kA: input moments (63 accumulators), block partials [63][1024]
__global__ __launch_bounds__(256) void kA(const float* __restrict__ rot, const float* __restrict__ tra,
                                          float* __restrict__ pA, int N){
  float a[63];
#pragma unroll
  for(int i=0;i<63;i++) a[i]=0.f;
  int stride = gridDim.x*blockDim.x;
  for(int row=blockIdx.x*blockDim.x+threadIdx.x; row<N; row+=stride){
    float t[3], r[9];
#pragma unroll
    for(int i=0;i<3;i++) t[i]=tra[row*3+i];
#pragma unroll
    for(int i=0;i<9;i++) r[i]=rot[row*9+i];
#pragma unroll
    for(int i=0;i<3;i++) a[i]+=t[i];
#pragma unroll
    for(int i=0;i<3;i++)
#pragma unroll
      for(int j=i;j<3;j++) a[3 + i*3 - (i*(i-1))/2 + (j-i)] += t[i]*t[j];
#pragma unroll
    for(int i=0;i<9;i++) a[9+i]+=r[i];
#pragma unroll
    for(int i=0;i<9;i++)
#pragma unroll
      for(int j=i;j<9;j++) a[18 + i*9 - (i*(i-1))/2 + (j-i)] += r[i]*r[j];
  }
#pragma unroll
  for(int i=0;i<63;i++) a[i]=wred(a[i]);
  __shared__ float lds[4][63];
  int wave=threadIdx.x>>6, lane=threadIdx.x&63;
  if(lane==0){
#pragma unroll
    for(int i=0;i<63;i++) lds[wave][i]=a[i];
  }
  __syncthreads();
  int t=threadIdx.x;
  if(t<63) pA[t*gridDim.x + blockIdx.x] = lds[0][t]+lds[1][t]+lds[2][t]+lds[3][t];
}

// ---------------- kA2: reduce moment partials, compute folded BN1 scale/bias for k/q/v
__global__ __launch_bounds__(256) void kA2(const float* __restrict__ pA, int nb,
    const float* __restrict__ kW1, const float* __restrict__ kg, const float* __restrict__ kb,
    const float* __restrict__ qW1, const float* __restrict__ qg, const float* __restrict__ qb,
    const float* __restrict__ vW1, const float* __restrict__ vg, const float* __restrict__ vb,
    float* __restrict__ cst, float invN){
  __shared__ float tmp[63][4];
  __shared__ float mom[63];
  int t=threadIdx.x;
  if(t<252){
    int f=t>>2, q=t&3;
    int per=nb/4;
    float s=0.f;
    for(int i=0;i<per;i++) s+=pA[f*nb + q*per + i];
    tmp[f][q]=s;
  }
  __syncthreads();
  if(t<63) mom[t]=tmp[t][0]+tmp[t][1]+tmp[t][2]+tmp[t][3];
  __syncthreads();
  if(t<96){
    int net=t>>5, j=t&31;
    const float* W1; const float* g; const float* b; int din, sbase, mbase, obase;
    if(net==0){W1=kW1;g=kg;b=kb;din=3;sbase=0;mbase=3;obase=0;}
    else if(net==1){W1=qW1;g=qg;b=qb;din=9;sbase=9;mbase=18;obase=64;}
    else {W1=vW1;g=vg;b=vb;din=3;sbase=0;mbase=3;obase=128;}
    float mean=0.f, ex2=0.f;
    for(int i=0;i<din;i++){
      float wi=W1[i*32+j];
      mean += mom[sbase+i]*wi;
      int rowb = mbase + i*din - (i*(i-1))/2;
      for(int i2=i;i2<din;i2++){
        float w2=W1[i2*32+j];
        float m=mom[rowb + (i2-i)];
        ex2 += ((i2==i)?1.f:2.f)*wi*w2*m;
      }
    }
    mean*=invN; ex2*=invN;
    float var=ex2-mean*mean;
    float sc=g[j]*rsqrtf(var+EPS);
    float bi=b[j]-mean*sc;
    cst[obase+j]=sc; cst[obase+32+j]=bi;
  }
}

// ---------------- kRed: reduce per-block {sum,sumsq} partials -> BN scale/bias
__global__ __launch_bounds__(256) void kRed(const float* __restrict__ part, int nf, int nb,
    const float* __restrict__ g, const float* __restrict__ b, float* __restrict__ cstOut, float invN){
  int f=blockIdx.x;
  float s1=0.f,s2=0.f;
  for(int i=threadIdx.x;i<nb;i+=256){ s1+=part[f*nb+i]; s2+=part[(nf+f)*nb+i]; }
  s1=wred(s1); s2=wred(s2);
  __shared__ float l1[4],l2[4];
  int wave=threadIdx.x>>6;
  if((threadIdx.x&63)==0){l1[wave]=s1;l2[wave]=s2;}
  __syncthreads();
  if(threadIdx.x==0){
    float a=l1[0]+l1[1]+l1[2]+l1[3];
    float c=l2[0]+l2[1]+l2[2]+l2[3];
    float mean=a*invN;
    float var=c*invN-mean*mean;
    float sc=g[f]*rsqrtf(var+EPS);
    float bi=b[f]-mean*sc;
    cstOut[f]=sc; cstOut[nf+f]=bi;
  }
}

// ---------------- kHeavy: per-row pipeline, all 64-dim state in NAMED scalars (no scratch).
// TAIL=0: y1 (+store,+stats). TAIL=1: ->y2 stats. TAIL=2: ->out.
template<int TAIL, int STORE>
__global__ __launch_bounds__(256) void kHeavy(
    const float* __restrict__ rot, const float* __restrict__ tra,
    const float* __restrict__ kW1, const float* __restrict__ qW1, const float* __restrict__ vW1,
    const float* __restrict__ kb2, const float* __restrict__ qb2, const float* __restrict__ vb2,
    const float* __restrict__ W2T, const float* __restrict__ dW1,
    const float* __restrict__ dW3, const float* __restrict__ db3,
    const float* __restrict__ cst,
    unsigned short* __restrict__ y1o, float* __restrict__ pOut, float* __restrict__ outp, int N)
{
  const float* kW2T=W2T;
  const float* qW2T=W2T+2048;
  const float* vW2T=W2T+4096;
  const float* dW2T=W2T+6144;
  int row=blockIdx.x*256+threadIdx.x;
  bool valid=row<N;
  int lrow=valid?row:0;
  float t0=tra[lrow*3+0], t1=tra[lrow*3+1], t2=tra[lrow*3+2];
  float r[9];
#pragma unroll
  for(int i=0;i<9;i++) r[i]=rot[lrow*9+i];
  float hk[32],hq[32];
#pragma unroll
  for(int j=0;j<32;j++){
    float x=t0*kW1[j]+t1*kW1[32+j]+t2*kW1[64+j];
    x=x*cst[j]+cst[32+j];
    hk[j]=x>0.f?x:0.f;
  }
#pragma unroll
  for(int j=0;j<32;j++){
    float x=0.f;
#pragma unroll
    for(int i=0;i<9;i++) x+=r[i]*qW1[i*32+j];
    x=x*cst[64+j]+cst[96+j];
    hq[j]=x>0.f?x:0.f;
  }
  // ---- s_j = (hk.kW2T[j]+kb2)*(hq.qW2T[j]+qb2), j=0..63 as named scalars ----
#define DECLS(j) float s_##j;
  REP64(DECLS)
#undef DECLS
#define KQC(j) { float kj=kb2[j], qj=qb2[j]; \
  _Pragma("unroll") for(int i=0;i<32;i++){ kj+=hk[i]*kW2T[(j)*32+i]; qj+=hq[i]*qW2T[(j)*32+i]; } \
  s_##j = kj*qj; }
  REP64(KQC)
#undef KQC
  // softmax (4-way partial trees)
  float m0=s_0, m1=s_1, m2=s_2, m3=s_3;
#define MXX(j) { if(((j)&3)==0) m0=fmaxf(m0,s_##j); else if(((j)&3)==1) m1=fmaxf(m1,s_##j); \
  else if(((j)&3)==2) m2=fmaxf(m2,s_##j); else m3=fmaxf(m3,s_##j); }
  REP64(MXX)
#undef MXX
  float mx=fmaxf(fmaxf(m0,m1),fmaxf(m2,m3));
  float z0=0.f,z1=0.f,z2=0.f,z3=0.f;
#define EXPX(j) { s_##j=__expf(s_##j-mx); if(((j)&3)==0) z0+=s_##j; else if(((j)&3)==1) z1+=s_##j; \
  else if(((j)&3)==2) z2+=s_##j; else z3+=s_##j; }
  REP64(EXPX)
#undef EXPX
  float inv=1.f/((z0+z1)+(z2+z3));
  float hv[32];
#pragma unroll
  for(int j=0;j<32;j++){
    float x=t0*vW1[j]+t1*vW1[32+j]+t2*vW1[64+j];
    x=x*cst[128+j]+cst[160+j];
    hv[j]=x>0.f?x:0.f;
  }
  float y1[32];
#pragma unroll
  for(int i=0;i<32;i++) y1[i]=0.f;
#define Y1X(j) { float vj=vb2[j]; \
  _Pragma("unroll") for(int i=0;i<32;i++) vj+=hv[i]*vW2T[(j)*32+i]; \
  float a=s_##j*inv*vj; \
  _Pragma("unroll") for(int i=0;i<32;i++) y1[i]+=a*dW1[(j)*32+i]; }
  REP64(Y1X)
#undef Y1X
  if(!valid){
#pragma unroll
    for(int i=0;i<32;i++) y1[i]=0.f;
  }
  if constexpr (TAIL==0){
    if constexpr (STORE){
      if(valid){
        unsigned int w[16];
#pragma unroll
        for(int kk=0;kk<16;kk++) w[kk]=(unsigned int)f2bf(y1[2*kk])|((unsigned int)f2bf(y1[2*kk+1])<<16);
        uint4* dst=(uint4*)(y1o+(size_t)row*32);
        dst[0]=make_uint4(w[0],w[1],w[2],w[3]);
        dst[1]=make_uint4(w[4],w[5],w[6],w[7]);
        dst[2]=make_uint4(w[8],w[9],w[10],w[11]);
        dst[3]=make_uint4(w[12],w[13],w[14],w[15]);
      }
    }
    __shared__ float lS[4][32], lQ[4][32];
    int wave=threadIdx.x>>6, lane=threadIdx.x&63;
#pragma unroll
    for(int i=0;i<32;i++){
      float sm=wred(y1[i]);
      float sq=wred(y1[i]*y1[i]);
      if(lane==0){lS[wave][i]=sm;lQ[wave][i]=sq;}
    }
    __syncthreads();
    if(threadIdx.x<32){
      int f=threadIdx.x;
      pOut[f*gridDim.x+blockIdx.x]=lS[0][f]+lS[1][f]+lS[2][f]+lS[3][f];
      pOut[(32+f)*gridDim.x+blockIdx.x]=lQ[0][f]+lQ[1][f]+lQ[2][f]+lQ[3][f];
    }
  } else {
    float h2[32];
#pragma unroll
    for(int i=0;i<32;i++){
      float x=y1[i]*cst[192+i]+cst[224+i];
      h2[i]=x>0.f?x:0.f;
    }
    float y2[16];
#define Y2X(j) { float acc=0.f; \
  _Pragma("unroll") for(int i=0;i<32;i++) acc+=h2[i]*dW2T[(j)*32+i]; \
  y2[j]=valid?acc:0.f; }
    REP16(Y2X)
#undef Y2X
    if constexpr (TAIL==1){
      __shared__ float lS[4][16], lQ[4][16];
      int wave=threadIdx.x>>6, lane=threadIdx.x&63;
#pragma unroll
      for(int i=0;i<16;i++){
        float sm=wred(y2[i]);
        float sq=wred(y2[i]*y2[i]);
        if(lane==0){lS[wave][i]=sm;lQ[wave][i]=sq;}
      }
      __syncthreads();
      if(threadIdx.x<16){
        int f=threadIdx.x;
        pOut[f*gridDim.x+blockIdx.x]=lS[0][f]+lS[1][f]+lS[2][f]+lS[3][f];
        pOut[(16+f)*gridDim.x+blockIdx.x]=lQ[0][f]+lQ[1][f]+lQ[2][f]+lQ[3][f];
      }
    } else {
      if(valid){
        float o=db3[0];
#pragma unroll
        for(int j=0;j<16;j++){
          float x=y2[j]*cst[256+j]+cst[272+j];
          x=x>0.f?x:0.f;
          o+=x*dW3[j];
        }
        outp[row]=1.f/(1.f+__expf(-o));
      }
    }
  }
}

// ---------------- kC: y1(bf16) -> BN-d1 -> ReLU -> dW2 -> y2(bf16) + stats
__global__ __launch_bounds__(256) void kC(const unsigned short* __restrict__ y1,
    const float* __restrict__ cst, const float* __restrict__ dW2T,
    unsigned short* __restrict__ y2, float* __restrict__ pC, int N){
  int row=blockIdx.x*256+threadIdx.x;
  bool valid=row<N;
  int lrow=valid?row:0;
  const uint4* src=(const uint4*)(y1+(size_t)lrow*32);
  uint4 q0=src[0],q1=src[1],q2=src[2],q3=src[3];
  unsigned int w[16]={q0.x,q0.y,q0.z,q0.w,q1.x,q1.y,q1.z,q1.w,
                      q2.x,q2.y,q2.z,q2.w,q3.x,q3.y,q3.z,q3.w};
  float h[32];
#pragma unroll
  for(int kk=0;kk<16;kk++){
    float lo=bflo(w[kk]), hi=bfhi(w[kk]);
    float a=lo*cst[192+2*kk]+cst[224+2*kk];
    float b=hi*cst[192+2*kk+1]+cst[224+2*kk+1];
    h[2*kk]  = a>0.f?a:0.f;
    h[2*kk+1]= b>0.f?b:0.f;
  }
  float y[16];
#define Y2CX(j) { float acc=0.f; \
  _Pragma("unroll") for(int i=0;i<32;i++) acc+=h[i]*dW2T[(j)*32+i]; \
  y[j]=valid?acc:0.f; }
  REP16(Y2CX)
#undef Y2CX
  if(valid){
    unsigned int o[8];
#pragma unroll
    for(int kk=0;kk<8;kk++) o[kk]=(unsigned int)f2bf(y[2*kk])|((unsigned int)f2bf(y[2*kk+1])<<16);
    uint4* dst=(uint4*)(y2+(size_t)row*16);
    dst[0]=make_uint4(o[0],o[1],o[2],o[3]);
    dst[1]=make_uint4(o[4],o[5],o[6],o[7]);
  }
  __shared__ float lS[4][16], lQ[4][16];
  int wave=threadIdx.x>>6, lane=threadIdx.x&63;
#pragma unroll
  for(int i=0;i<16;i++){
    float sm=wred(y[i]);
    float sq=wred(y[i]*y[i]);
    if(lane==0){lS[wave][i]=sm;lQ[wave][i]=sq;}
  }
  __syncthreads();
  if(threadIdx.x<16){
    int f=threadIdx.x;
    pC[f*gridDim.x+blockIdx.x]=lS[0][f]+lS[1][f]+lS[2][f]+lS[3][f];
    pC[(16+f)*gridDim.x+blockIdx.x]=lQ[0][f]+lQ[1][f]+lQ[2][f]+lQ[3][f];
  }
}

// ---------------- kD: y2(bf16) -> BN-d2 -> ReLU -> dW3+db3 -> sigmoid -> out
__global__ __launch_bounds__(256) void kD(const unsigned short* __restrict__ y2,
    const float* __restrict__ cst, const float* __restrict__ dW3, const float* __restrict__ db3,
    float* __restrict__ outp, int N){
  int row=blockIdx.x*256+threadIdx.x;
  if(row>=N) return;
  const uint4* src=(const uint4*)(y2+(size_t)row*16);
  uint4 q0=src[0],q1=src[1];
  unsigned int w[8]={q0.x,q0.y,q0.z,q0.w,q1.x,q1.y,q1.z,q1.w};
  float o=db3[0];
#pragma unroll
  for(int kk=0;kk<8;kk++){
    float lo=bflo(w[kk])*cst[256+2*kk]+cst[272+2*kk];
    float hi=bfhi(w[kk])*cst[256+2*kk+1]+cst[272+2*kk+1];
    lo=lo>0.f?lo:0.f; hi=hi>0.f?hi:0.f;
    o+=lo*dW3[2*kk]+hi*dW3[2*kk+1];
  }
  outp[row]=1.f/(1.f+__expf(-o));
}

extern "C" void kernel_launch(void* const* d_in, const int* in_sizes, int n_in,
                              void* d_out, int out_size, void* d_ws, size_t ws_size,
                              hipStream_t stream){
  const float* rot=(const float*)d_in[0];
  const float* tra=(const float*)d_in[1];
  const float* kW1=(const float*)d_in[2];
  const float* kg =(const float*)d_in[3];
  const float* kb =(const float*)d_in[4];
  const float* kW2=(const float*)d_in[5];
  const float* kb2=(const float*)d_in[6];
  const float* qW1=(const float*)d_in[7];
  const float* qg =(const float*)d_in[8];
  const float* qb =(const float*)d_in[9];
  const float* qW2=(const float*)d_in[10];
  const float* qb2=(const float*)d_in[11];
  const float* vW1=(const float*)d_in[12];
  const float* vg =(const float*)d_in[13];
  const float* vb =(const float*)d_in[14];
  const float* vW2=(const float*)d_in[15];
  const float* vb2=(const float*)d_in[16];
  const float* dW1=(const float*)d_in[17];
  const float* dg1=(const float*)d_in[18];
  const float* db1=(const float*)d_in[19];
  const float* dW2=(const float*)d_in[20];
  const float* dg2=(const float*)d_in[21];
  const float* db2=(const float*)d_in[22];
  const float* dW3=(const float*)d_in[23];
  const float* db3=(const float*)d_in[24];

  int N=in_sizes[0]/9;
  int nb=(N+255)/256;

  float* ws=(float*)d_ws;
  float* cst=ws;                       // 1024 floats (BN consts)
  float* pA =ws+1024;                  // [63][1024]
  float* pB =ws+65536;                 // [64][nb]
  float* pC =pB+(size_t)64*nb;         // [32][nb]
  float* pW =pC+(size_t)32*nb;         // 6656 floats (transposed weights)

  size_t y1off=(size_t)8<<20;          // bytes; partials+consts end well below 8 MiB for nb=8192
  unsigned short* y1=(unsigned short*)((char*)d_ws + y1off);
  unsigned short* y2=(unsigned short*)((char*)d_ws + y1off + (size_t)N*64);
  size_t need=y1off + (size_t)N*64 + (size_t)N*32;
  bool store = ws_size>=need;
  float invN=1.f/(float)N;
  dim3 B(256);

  kT <<<dim3(1),   B,0,stream>>>(kW2,qW2,vW2,dW2,pW);
  kA <<<dim3(1024),B,0,stream>>>(rot,tra,pA,N);
  kA2<<<dim3(1),   B,0,stream>>>(pA,1024,kW1,kg,kb,qW1,qg,qb,vW1,vg,vb,cst,invN);

  if(store){
    kHeavy<0,1><<<dim3(nb),B,0,stream>>>(rot,tra,kW1,qW1,vW1,kb2,qb2,vb2,pW,dW1,dW3,db3,cst,y1,pB,nullptr,N);
    kRed<<<dim3(32),B,0,stream>>>(pB,32,nb,dg1,db1,cst+192,invN);
    kC  <<<dim3(nb),B,0,stream>>>(y1,cst,pW+6144,y2,pC,N);
    kRed<<<dim3(16),B,0,stream>>>(pC,16,nb,dg2,db2,cst+256,invN);
    kD  <<<dim3(nb),B,0,stream>>>(y2,cst,dW3,db3,(float*)d_out,N);
  } else {
    kHeavy<0,0><<<dim3(nb),B,0,stream>>>(rot,tra,kW1,qW1,vW1,kb2,qb2,vb2,pW,dW1,dW3,db3,cst,nullptr,pB,nullptr,N);
    kRed<<<dim3(32),B,0,stream>>>(pB,32,nb,dg1,db1,cst+192,invN);
    kHeavy<1,0><<<dim3(nb),B,0,stream>>>(rot,tra,kW1,qW1,vW1,kb2,qb2,vb2,pW,dW1,dW3,db3,cst,nullptr,pC,nullptr,N);
    kRed<<<dim3(16),B,0,stream>>>(pC,16,nb,dg2,db2,cst+256,invN);
    kHeavy<2,0><<<dim3(nb),B,0,stream>>>(rot,tra,kW1,qW1,vW1,kb2,qb2,vb2,pW,dW1,dW3,db3,cst,nullptr,nullptr,(float*)d_out,N);
  }
}

// Round 7
// 540.481 us; speedup vs baseline: 5.2334x; 5.0085x over previous
//
#include <hip/hip_runtime.h>

#define EPS 1e-5f

typedef __attribute__((ext_vector_type(8))) short short8;
typedef __attribute__((ext_vector_type(4))) float f32x4;
#define MFMA16(a,b,c) __builtin_amdgcn_mfma_f32_16x16x32_bf16(a,b,c,0,0,0)

union U8 { short8 s; uint4 u; };

__device__ __forceinline__ float wred(float v){
#pragma unroll
  for(int m=32;m>=1;m>>=1) v += __shfl_xor(v,m,64);
  return v;
}

__device__ __forceinline__ unsigned short f2bf(float f){
  union{unsigned int i; float x;}v; v.x=f;
  unsigned int u=v.i;
  unsigned int r=(u + 0x7fffu + ((u>>16)&1u))>>16;
  return (unsigned short)r;
}
__device__ __forceinline__ unsigned pk2(float lo, float hi){
  return (unsigned)f2bf(lo) | ((unsigned)f2bf(hi)<<16);
}
__device__ __forceinline__ float bflo(unsigned int u){
  union{unsigned int i; float x;}v; v.i=u<<16; return v.x;
}
__device__ __forceinline__ float bfhi(unsigned int u){
  union{unsigned int i; float x;}v; v.i=u&0xffff0000u; return v.x;
}

// ---------------- kT: build bf16 transposed weights for MFMA b-fragments
// wbf layout (shorts): kW2T[64][32] @0 | qW2T @2048 | vW2T @4096 | dW1T[32][64] @6144 | dW2T[16][32] @8192
__global__ __launch_bounds__(256) void kT(const float* __restrict__ kW2, const float* __restrict__ qW2,
                                          const float* __restrict__ vW2, const float* __restrict__ dW1,
                                          const float* __restrict__ dW2,
                                          unsigned short* __restrict__ wbf){
  for(int idx=threadIdx.x; idx<2048; idx+=256){
    int k=idx>>6, c=idx&63;            // W2 is [32][64]
    wbf[c*32+k]       = f2bf(kW2[idx]);
    wbf[2048+c*32+k]  = f2bf(qW2[idx]);
    wbf[4096+c*32+k]  = f2bf(vW2[idx]);
  }
  for(int idx=threadIdx.x; idx<2048; idx+=256){
    int k=idx>>5, f=idx&31;            // dW1 is [64][32]
    wbf[6144 + f*64 + k] = f2bf(dW1[idx]);
  }
  for(int idx=threadIdx.x; idx<512; idx+=256){
    int k=idx>>4, f=idx&15;            // dW2 is [32][16]
    wbf[8192 + f*32 + k] = f2bf(dW2[idx]);
  }
}

// ---------------- kA: input moments (63 accumulators), block partials [63][1024]
__global__ __launch_bounds__(256) void kA(const float* __restrict__ rot, const float* __restrict__ tra,
                                          float* __restrict__ pA, int N){
  float a[63];
#pragma unroll
  for(int i=0;i<63;i++) a[i]=0.f;
  int stride = gridDim.x*blockDim.x;
  for(int row=blockIdx.x*blockDim.x+threadIdx.x; row<N; row+=stride){
    float t[3], r[9];
#pragma unroll
    for(int i=0;i<3;i++) t[i]=tra[row*3+i];
#pragma unroll
    for(int i=0;i<9;i++) r[i]=rot[row*9+i];
#pragma unroll
    for(int i=0;i<3;i++) a[i]+=t[i];
#pragma unroll
    for(int i=0;i<3;i++)
#pragma unroll
      for(int j=i;j<3;j++) a[3 + i*3 - (i*(i-1))/2 + (j-i)] += t[i]*t[j];
#pragma unroll
    for(int i=0;i<9;i++) a[9+i]+=r[i];
#pragma unroll
    for(int i=0;i<9;i++)
#pragma unroll
      for(int j=i;j<9;j++) a[18 + i*9 - (i*(i-1))/2 + (j-i)] += r[i]*r[j];
  }
#pragma unroll
  for(int i=0;i<63;i++) a[i]=wred(a[i]);
  __shared__ __align__(16) float lds[4][63];
  int wave=threadIdx.x>>6, lane=threadIdx.x&63;
  if(lane==0){
#pragma unroll
    for(int i=0;i<63;i++) lds[wave][i]=a[i];
  }
  __syncthreads();
  int t=threadIdx.x;
  if(t<63) pA[t*gridDim.x + blockIdx.x] = lds[0][t]+lds[1][t]+lds[2][t]+lds[3][t];
}

// ---------------- kA2: reduce moments -> folded BN1 scale/bias; write folded W1f (FIXED: full 480 write)
__global__ __launch_bounds__(256) void kA2(const float* __restrict__ pA, int nb,
    const float* __restrict__ kW1, const float* __restrict__ kg, const float* __restrict__ kb,
    const float* __restrict__ qW1, const float* __restrict__ qg, const float* __restrict__ qb,
    const float* __restrict__ vW1, const float* __restrict__ vg, const float* __restrict__ vb,
    float* __restrict__ cst, float* __restrict__ wf, float invN){
  __shared__ __align__(16) float tmp[63][4];
  __shared__ __align__(16) float mom[63];
  __shared__ __align__(16) float sSc[96];
  int t=threadIdx.x;
  if(t<252){
    int f=t>>2, q=t&3;
    int per=nb/4;
    float s=0.f;
    for(int i=0;i<per;i++) s+=pA[f*nb + q*per + i];
    tmp[f][q]=s;
  }
  __syncthreads();
  if(t<63) mom[t]=tmp[t][0]+tmp[t][1]+tmp[t][2]+tmp[t][3];
  __syncthreads();
  if(t<96){
    int net=t>>5, j=t&31;
    const float* W1; const float* g; const float* b; int din, sbase, mbase, obase;
    if(net==0){W1=kW1;g=kg;b=kb;din=3;sbase=0;mbase=3;obase=0;}
    else if(net==1){W1=qW1;g=qg;b=qb;din=9;sbase=9;mbase=18;obase=64;}
    else {W1=vW1;g=vg;b=vb;din=3;sbase=0;mbase=3;obase=128;}
    float mean=0.f, ex2=0.f;
    for(int i=0;i<din;i++){
      float wi=W1[i*32+j];
      mean += mom[sbase+i]*wi;
      int rowb = mbase + i*din - (i*(i-1))/2;
      for(int i2=i;i2<din;i2++){
        float w2=W1[i2*32+j];
        float m=mom[rowb + (i2-i)];
        ex2 += ((i2==i)?1.f:2.f)*wi*w2*m;
      }
    }
    mean*=invN; ex2*=invN;
    float var=ex2-mean*mean;
    float sc=g[j]*rsqrtf(var+EPS);
    float bi=b[j]-mean*sc;
    cst[obase+j]=sc; cst[obase+32+j]=bi;
    sSc[net*32+j]=sc;
  }
  __syncthreads();
  // folded W1: wf[0..95]=kW1*sc, [96..383]=qW1*sc, [384..479]=vW1*sc
  // FIX (R5 root cause): block has 256 threads but 480 entries -> must LOOP, not guard.
  for(int i=threadIdx.x; i<480; i+=256){
    float v;
    if(i<96)       v = kW1[i]      * sSc[i&31];
    else if(i<384) v = qW1[i-96]   * sSc[32+((i-96)&31)];
    else           v = vW1[i-384]  * sSc[64+((i-384)&31)];
    wf[i]=v;
  }
}

// ---------------- kRed: reduce per-block {sum,sumsq} partials -> BN scale/bias
__global__ __launch_bounds__(256) void kRed(const float* __restrict__ part, int nf, int nb,
    const float* __restrict__ g, const float* __restrict__ b, float* __restrict__ cstOut, float invN){
  int f=blockIdx.x;
  float s1=0.f,s2=0.f;
  for(int i=threadIdx.x;i<nb;i+=256){ s1+=part[f*nb+i]; s2+=part[(nf+f)*nb+i]; }
  s1=wred(s1); s2=wred(s2);
  __shared__ __align__(16) float l1[4],l2[4];
  int wave=threadIdx.x>>6;
  if((threadIdx.x&63)==0){l1[wave]=s1;l2[wave]=s2;}
  __syncthreads();
  if(threadIdx.x==0){
    float a=l1[0]+l1[1]+l1[2]+l1[3];
    float c=l2[0]+l2[1]+l2[2]+l2[3];
    float mean=a*invN;
    float var=c*invN-mean*mean;
    float sc=g[f]*rsqrtf(var+EPS);
    float bi=b[f]-mean*sc;
    cstOut[f]=sc; cstOut[nf+f]=bi;
  }
}

// ---------------- kHeavyM: MFMA per-row pipeline -> y1(bf16) + BN-d1 stats
// 4 waves/block, each wave: 16 tiles of 16 rows => block covers 1024 rows.
// D layout (verified on-HW by R2==R4 probe equivalence): row=4*(lane>>4)+reg, col=lane&15.
__global__ __launch_bounds__(256) void kHeavyM(
    const float* __restrict__ rot, const float* __restrict__ tra,
    const float* __restrict__ cst, const float* __restrict__ wf,
    const unsigned short* __restrict__ wbf,
    const float* __restrict__ kb2, const float* __restrict__ qb2, const float* __restrict__ vb2,
    unsigned short* __restrict__ y1o, float* __restrict__ pB, int N, int nb)
{
  __shared__ __align__(16) float sW[480];
  __shared__ __align__(16) float pbuf[4][1024];          // per-wave 16x64 f32 (swizzled)
  __shared__ __align__(16) unsigned short ybuf[4][512];  // per-wave 16x32 bf16 (swizzled)
  __shared__ __align__(16) float sStat[4][64];
  for(int i=threadIdx.x;i<480;i+=256) sW[i]=wf[i];
  int wv=threadIdx.x>>6, lane=threadIdx.x&63;
  int c=lane&15, g=lane>>4;

  // resident b-fragments (bf16x8 per lane)
  U8 bK[4],bQ[4],bV[4],bD[2][2];
#pragma unroll
  for(int t=0;t<4;t++){
    bK[t].u = *(const uint4*)(wbf +        (t*16+c)*32 + 8*g);
    bQ[t].u = *(const uint4*)(wbf + 2048 + (t*16+c)*32 + 8*g);
    bV[t].u = *(const uint4*)(wbf + 4096 + (t*16+c)*32 + 8*g);
  }
#pragma unroll
  for(int kc=0;kc<2;kc++)
#pragma unroll
    for(int nt=0;nt<2;nt++)
      bD[kc][nt].u = *(const uint4*)(wbf + 6144 + (nt*16+c)*64 + kc*32 + 8*g);

  // resident biases
  float bk2[4],bq2[4],bv2[4];
#pragma unroll
  for(int t=0;t<4;t++){ bk2[t]=kb2[t*16+c]; bq2[t]=qb2[t*16+c]; bv2[t]=vb2[t*16+c]; }
  float bbk[8],bbq[8],bbv[8];
#pragma unroll
  for(int i=0;i<8;i++){
    bbk[i]=cst[32+8*g+i];
    bbq[i]=cst[96+8*g+i];
    bbv[i]=cst[160+8*g+i];
  }

  float stS0=0.f, stS1=0.f, stQ0=0.f, stQ1=0.f;
  __syncthreads();

  float* pb = pbuf[wv];
  unsigned short* yb = ybuf[wv];
  int tileBase = blockIdx.x*1024 + wv*16;
  for(int it=0; it<16; ++it, tileBase += 64){
    if(tileBase >= N) break;             // no barriers inside loop (wave-private LDS)
    int row = tileBase + c;
    bool vrow = row < N;
    int lr = vrow ? row : 0;
    float t0=tra[lr*3+0], t1=tra[lr*3+1], t2=tra[lr*3+2];
    float rr[9];
#pragma unroll
    for(int i=0;i<9;i++) rr[i]=rot[lr*9+i];

    // first layers (folded BN1), 8 k-slots per lane
    float hk[8],hq[8],hv[8];
#pragma unroll
    for(int i=0;i<8;i++){ hk[i]=bbk[i]; hq[i]=bbq[i]; hv[i]=bbv[i]; }
#pragma unroll
    for(int i=0;i<3;i++){
      float xi = (i==0)?t0:((i==1)?t1:t2);
#pragma unroll
      for(int j=0;j<8;j++){
        hk[j]+=xi*sW[i*32+8*g+j];
        hv[j]+=xi*sW[384+i*32+8*g+j];
      }
    }
#pragma unroll
    for(int i=0;i<9;i++){
      float xi = rr[i];
#pragma unroll
      for(int j=0;j<8;j++) hq[j]+=xi*sW[96+i*32+8*g+j];
    }
    U8 aK,aQ,aV;
#pragma unroll
    for(int i=0;i<8;i++){ hk[i]=fmaxf(hk[i],0.f); hq[i]=fmaxf(hq[i],0.f); hv[i]=fmaxf(hv[i],0.f); }
    aK.u = make_uint4(pk2(hk[0],hk[1]),pk2(hk[2],hk[3]),pk2(hk[4],hk[5]),pk2(hk[6],hk[7]));
    aQ.u = make_uint4(pk2(hq[0],hq[1]),pk2(hq[2],hq[3]),pk2(hq[4],hq[5]),pk2(hq[6],hq[7]));
    aV.u = make_uint4(pk2(hv[0],hv[1]),pk2(hv[2],hv[3]),pk2(hv[4],hv[5]),pk2(hv[6],hv[7]));

    // k,q GEMMs -> s = (k+kb2)*(q+qb2)   [D layout: row m=4g+rg, col n=16t+c]
    f32x4 z4 = {0.f,0.f,0.f,0.f};
    f32x4 ack[4], acq[4];
#pragma unroll
    for(int t=0;t<4;t++) ack[t]=MFMA16(aK.s, bK[t].s, z4);
#pragma unroll
    for(int t=0;t<4;t++) acq[t]=MFMA16(aQ.s, bQ[t].s, z4);
    f32x4 s4[4];
#pragma unroll
    for(int t=0;t<4;t++)
#pragma unroll
      for(int rg=0;rg<4;rg++) s4[t][rg]=(ack[t][rg]+bk2[t])*(acq[t][rg]+bq2[t]);

    // softmax over n (4 tiles x 16 lanes within group)
    f32x4 mx = s4[0];
#pragma unroll
    for(int t=1;t<4;t++)
#pragma unroll
      for(int rg=0;rg<4;rg++) mx[rg]=fmaxf(mx[rg],s4[t][rg]);
#pragma unroll
    for(int m=8;m>=1;m>>=1)
#pragma unroll
      for(int rg=0;rg<4;rg++) mx[rg]=fmaxf(mx[rg],__shfl_xor(mx[rg],m,64));
    f32x4 zz = z4;
#pragma unroll
    for(int t=0;t<4;t++)
#pragma unroll
      for(int rg=0;rg<4;rg++){ float e=__expf(s4[t][rg]-mx[rg]); s4[t][rg]=e; zz[rg]+=e; }
#pragma unroll
    for(int m=8;m>=1;m>>=1)
#pragma unroll
      for(int rg=0;rg<4;rg++) zz[rg]+=__shfl_xor(zz[rg],m,64);
    f32x4 inv;
#pragma unroll
    for(int rg=0;rg<4;rg++) inv[rg]=1.f/zz[rg];

    // v GEMM, P = e*inv*(v+vb2) -> swizzled LDS
    f32x4 acv[4];
#pragma unroll
    for(int t=0;t<4;t++) acv[t]=MFMA16(aV.s, bV[t].s, z4);
#pragma unroll
    for(int t=0;t<4;t++)
#pragma unroll
      for(int rg=0;rg<4;rg++){
        float P = s4[t][rg]*inv[rg]*(acv[t][rg]+bv2[t]);
        int m = 4*g+rg, n = 16*t+c;
        pb[(m*64 + n) ^ ((m&7)<<3)] = P;
      }

    // y1 = P @ dW1 (a-frags read back from LDS)
    f32x4 acy0=z4, acy1=z4;
#pragma unroll
    for(int kc=0;kc<2;kc++){
      int idx = (c*64 + 32*kc + 8*g) ^ ((c&7)<<3);
      float p0=pb[idx+0], p1=pb[idx+1], p2=pb[idx+2], p3=pb[idx+3];
      float p4=pb[idx+4], p5=pb[idx+5], p6=pb[idx+6], p7=pb[idx+7];
      U8 ap;
      ap.u = make_uint4(pk2(p0,p1),pk2(p2,p3),pk2(p4,p5),pk2(p6,p7));
      acy0 = MFMA16(ap.s, bD[kc][0].s, acy0);
      acy1 = MFMA16(ap.s, bD[kc][1].s, acy1);
    }
    // mask invalid rows
#pragma unroll
    for(int rg=0;rg<4;rg++){
      if(tileBase + 4*g + rg >= N){ acy0[rg]=0.f; acy1[rg]=0.f; }
    }
    // stats
#pragma unroll
    for(int rg=0;rg<4;rg++){
      stS0+=acy0[rg]; stQ0+=acy0[rg]*acy0[rg];
      stS1+=acy1[rg]; stQ1+=acy1[rg]*acy1[rg];
    }
    // y1 store via swizzled LDS -> coalesced 16B
#pragma unroll
    for(int rg=0;rg<4;rg++){
      int m=4*g+rg;
      yb[(m*32 + c)      ^ ((m&3)<<3)] = f2bf(acy0[rg]);
      yb[(m*32 + 16 + c) ^ ((m&3)<<3)] = f2bf(acy1[rg]);
    }
    {
      int idx = (c*32 + 8*g) ^ ((c&3)<<3);
      uint4 vv = *(uint4*)&yb[idx];
      if(vrow) *(uint4*)(y1o + (size_t)row*32 + 8*g) = vv;
    }
  }
  // block stats reduction: f = {c, 16+c} sums / sqs
  stS0+=__shfl_xor(stS0,16,64); stS0+=__shfl_xor(stS0,32,64);
  stS1+=__shfl_xor(stS1,16,64); stS1+=__shfl_xor(stS1,32,64);
  stQ0+=__shfl_xor(stQ0,16,64); stQ0+=__shfl_xor(stQ0,32,64);
  stQ1+=__shfl_xor(stQ1,16,64); stQ1+=__shfl_xor(stQ1,32,64);
  if(g==0){
    sStat[wv][c]=stS0; sStat[wv][16+c]=stS1;
    sStat[wv][32+c]=stQ0; sStat[wv][48+c]=stQ1;
  }
  __syncthreads();
  int t=threadIdx.x;
  if(t<64) pB[t*nb + blockIdx.x] = sStat[0][t]+sStat[1][t]+sStat[2][t]+sStat[3][t];
}

// ---------------- kCM: y1(bf16) -> BN-d1 -> ReLU -> dW2 (MFMA) -> y2(bf16) + stats
__global__ __launch_bounds__(256) void kCM(const unsigned short* __restrict__ y1,
    const float* __restrict__ cst, const unsigned short* __restrict__ wbf,
    unsigned short* __restrict__ y2o, float* __restrict__ pC, int N, int nb){
  __shared__ __align__(16) unsigned short ybuf[4][256];  // per-wave 16x16 bf16
  __shared__ __align__(16) float sStat[4][32];
  int wv=threadIdx.x>>6, lane=threadIdx.x&63;
  int c=lane&15, g=lane>>4;
  U8 bD2; bD2.u = *(const uint4*)(wbf + 8192 + c*32 + 8*g);
  float sc[8], bi[8];
#pragma unroll
  for(int i=0;i<8;i++){ sc[i]=cst[192+8*g+i]; bi[i]=cst[224+8*g+i]; }
  float stS=0.f, stQ=0.f;
  unsigned short* yb = ybuf[wv];
  int tileBase = blockIdx.x*1024 + wv*16;
  f32x4 z4 = {0.f,0.f,0.f,0.f};
  for(int it=0; it<16; ++it, tileBase += 64){
    if(tileBase >= N) break;
    int row = tileBase + c;
    bool vrow = row < N;
    int lr = vrow ? row : 0;
    uint4 w = *(const uint4*)(y1 + (size_t)lr*32 + 8*g);
    unsigned wu[4]={w.x,w.y,w.z,w.w};
    float h[8];
#pragma unroll
    for(int j=0;j<4;j++){ h[2*j]=bflo(wu[j]); h[2*j+1]=bfhi(wu[j]); }
#pragma unroll
    for(int i=0;i<8;i++){ float x=h[i]*sc[i]+bi[i]; h[i]=fmaxf(x,0.f); }
    U8 a;
    a.u = make_uint4(pk2(h[0],h[1]),pk2(h[2],h[3]),pk2(h[4],h[5]),pk2(h[6],h[7]));
    f32x4 acc = MFMA16(a.s, bD2.s, z4);
#pragma unroll
    for(int rg=0;rg<4;rg++){
      if(tileBase + 4*g + rg >= N) acc[rg]=0.f;
      stS+=acc[rg]; stQ+=acc[rg]*acc[rg];
    }
#pragma unroll
    for(int rg=0;rg<4;rg++){
      int m=4*g+rg;
      yb[(m*16 + c) ^ ((m&3)<<2)] = f2bf(acc[rg]);
    }
    {
      int idx = (c*16 + 4*g) ^ ((c&3)<<2);
      uint2 vv = *(uint2*)&yb[idx];
      if(vrow) *(uint2*)(y2o + (size_t)row*16 + 4*g) = vv;
    }
  }
  stS+=__shfl_xor(stS,16,64); stS+=__shfl_xor(stS,32,64);
  stQ+=__shfl_xor(stQ,16,64); stQ+=__shfl_xor(stQ,32,64);
  if(g==0){ sStat[wv][c]=stS; sStat[wv][16+c]=stQ; }
  __syncthreads();
  int t=threadIdx.x;
  if(t<32) pC[t*nb + blockIdx.x] = sStat[0][t]+sStat[1][t]+sStat[2][t]+sStat[3][t];
}

// ---------------- kD: y2(bf16) -> BN-d2 -> ReLU -> dW3+db3 -> sigmoid -> out
__global__ __launch_bounds__(256) void kD(const unsigned short* __restrict__ y2,
    const float* __restrict__ cst, const float* __restrict__ dW3, const float* __restrict__ db3,
    float* __restrict__ outp, int N){
  int row=blockIdx.x*256+threadIdx.x;
  if(row>=N) return;
  const uint4* src=(const uint4*)(y2+(size_t)row*16);
  uint4 q0=src[0],q1=src[1];
  unsigned int w[8]={q0.x,q0.y,q0.z,q0.w,q1.x,q1.y,q1.z,q1.w};
  float o=db3[0];
#pragma unroll
  for(int kk=0;kk<8;kk++){
    float lo=bflo(w[kk])*cst[256+2*kk]+cst[272+2*kk];
    float hi=bfhi(w[kk])*cst[256+2*kk+1]+cst[272+2*kk+1];
    lo=lo>0.f?lo:0.f; hi=hi>0.f?hi:0.f;
    o+=lo*dW3[2*kk]+hi*dW3[2*kk+1];
  }
  outp[row]=1.f/(1.f+__expf(-o));
}

extern "C" void kernel_launch(void* const* d_in, const int* in_sizes, int n_in,
                              void* d_out, int out_size, void* d_ws, size_t ws_size,
                              hipStream_t stream){
  const float* rot=(const float*)d_in[0];
  const float* tra=(const float*)d_in[1];
  const float* kW1=(const float*)d_in[2];
  const float* kg =(const float*)d_in[3];
  const float* kb =(const float*)d_in[4];
  const float* kW2=(const float*)d_in[5];
  const float* kb2=(const float*)d_in[6];
  const float* qW1=(const float*)d_in[7];
  const float* qg =(const float*)d_in[8];
  const float* qb =(const float*)d_in[9];
  const float* qW2=(const float*)d_in[10];
  const float* qb2=(const float*)d_in[11];
  const float* vW1=(const float*)d_in[12];
  const float* vg =(const float*)d_in[13];
  const float* vb =(const float*)d_in[14];
  const float* vW2=(const float*)d_in[15];
  const float* vb2=(const float*)d_in[16];
  const float* dW1=(const float*)d_in[17];
  const float* dg1=(const float*)d_in[18];
  const float* db1=(const float*)d_in[19];
  const float* dW2=(const float*)d_in[20];
  const float* dg2=(const float*)d_in[21];
  const float* db2=(const float*)d_in[22];
  const float* dW3=(const float*)d_in[23];
  const float* db3=(const float*)d_in[24];

  int N=in_sizes[0]/9;
  int nbH=(N+1023)/1024;

  float* ws=(float*)d_ws;
  float* cst=ws;                         // [0,1024)
  float* wf =ws+1024;                    // [1024,1536) folded W1
  float* pA =ws+1536;                    // 63*1024 -> ends 66048
  float* pB =ws+66048;                   // [64][nbH]
  float* pC =pB+(size_t)64*nbH;          // [32][nbH]
  unsigned short* wbf=(unsigned short*)(pC+(size_t)32*nbH);  // 8704 shorts

  size_t y1off=(size_t)8<<20;            // bytes
  unsigned short* y1=(unsigned short*)((char*)d_ws + y1off);
  unsigned short* y2=(unsigned short*)((char*)d_ws + y1off + (size_t)N*64);
  float invN=1.f/(float)N;
  dim3 B(256);

  kT <<<dim3(1),   B,0,stream>>>(kW2,qW2,vW2,dW1,dW2,wbf);
  kA <<<dim3(1024),B,0,stream>>>(rot,tra,pA,N);
  kA2<<<dim3(1),   B,0,stream>>>(pA,1024,kW1,kg,kb,qW1,qg,qb,vW1,vg,vb,cst,wf,invN);

  kHeavyM<<<dim3(nbH),B,0,stream>>>(rot,tra,cst,wf,wbf,kb2,qb2,vb2,y1,pB,N,nbH);
  kRed<<<dim3(32),B,0,stream>>>(pB,32,nbH,dg1,db1,cst+192,invN);
  kCM<<<dim3(nbH),B,0,stream>>>(y1,cst,wbf,y2,pC,N,nbH);
  kRed<<<dim3(16),B,0,stream>>>(pC,16,nbH,dg2,db2,cst+256,invN);
  kD <<<dim3((N+255)/256),B,0,stream>>>(y2,cst,dW3,db3,(float*)d_out,N);
}

// Round 8
// 488.154 us; speedup vs baseline: 5.7944x; 1.1072x over previous
//
#include <hip/hip_runtime.h>

#define EPS 1e-5f

typedef __attribute__((ext_vector_type(8))) short short8;
typedef __attribute__((ext_vector_type(4))) float f32x4;
#define MFMA16(a,b,c) __builtin_amdgcn_mfma_f32_16x16x32_bf16(a,b,c,0,0,0)

union U8 { short8 s; uint4 u; };

__device__ __forceinline__ float wred(float v){
#pragma unroll
  for(int m=32;m>=1;m>>=1) v += __shfl_xor(v,m,64);
  return v;
}

__device__ __forceinline__ unsigned short f2bf(float f){
  union{unsigned int i; float x;}v; v.x=f;
  unsigned int u=v.i;
  unsigned int r=(u + 0x7fffu + ((u>>16)&1u))>>16;
  return (unsigned short)r;
}
// single-instruction packed f32->bf16 (RNE). Verified bit-identical to f2bf pair on HW (R2==R3).
__device__ __forceinline__ unsigned cvtpk(float lo, float hi){
  unsigned r; asm("v_cvt_pk_bf16_f32 %0, %1, %2" : "=v"(r) : "v"(lo), "v"(hi)); return r;
}
__device__ __forceinline__ float bflo(unsigned int u){
  union{unsigned int i; float x;}v; v.i=u<<16; return v.x;
}
__device__ __forceinline__ float bfhi(unsigned int u){
  union{unsigned int i; float x;}v; v.i=u&0xffff0000u; return v.x;
}

// ---------------- kT: build bf16 transposed weights for MFMA b-fragments
// wbf layout (shorts): kW2T[64][32] @0 | qW2T @2048 | vW2T @4096 | dW1T[32][64] @6144 | dW2T[16][32] @8192
__global__ __launch_bounds__(256) void kT(const float* __restrict__ kW2, const float* __restrict__ qW2,
                                          const float* __restrict__ vW2, const float* __restrict__ dW1,
                                          const float* __restrict__ dW2,
                                          unsigned short* __restrict__ wbf){
  for(int idx=threadIdx.x; idx<2048; idx+=256){
    int k=idx>>6, c=idx&63;            // W2 is [32][64]
    wbf[c*32+k]       = f2bf(kW2[idx]);
    wbf[2048+c*32+k]  = f2bf(qW2[idx]);
    wbf[4096+c*32+k]  = f2bf(vW2[idx]);
  }
  for(int idx=threadIdx.x; idx<2048; idx+=256){
    int k=idx>>5, f=idx&31;            // dW1 is [64][32]
    wbf[6144 + f*64 + k] = f2bf(dW1[idx]);
  }
  for(int idx=threadIdx.x; idx<512; idx+=256){
    int k=idx>>4, f=idx&15;            // dW2 is [32][16]
    wbf[8192 + f*32 + k] = f2bf(dW2[idx]);
  }
}

// ---------------- kA: input moments (63 accumulators), block partials [63][1024]
__global__ __launch_bounds__(256) void kA(const float* __restrict__ rot, const float* __restrict__ tra,
                                          float* __restrict__ pA, int N){
  float a[63];
#pragma unroll
  for(int i=0;i<63;i++) a[i]=0.f;
  int stride = gridDim.x*blockDim.x;
  for(int row=blockIdx.x*blockDim.x+threadIdx.x; row<N; row+=stride){
    float t[3], r[9];
#pragma unroll
    for(int i=0;i<3;i++) t[i]=tra[row*3+i];
#pragma unroll
    for(int i=0;i<9;i++) r[i]=rot[row*9+i];
#pragma unroll
    for(int i=0;i<3;i++) a[i]+=t[i];
#pragma unroll
    for(int i=0;i<3;i++)
#pragma unroll
      for(int j=i;j<3;j++) a[3 + i*3 - (i*(i-1))/2 + (j-i)] += t[i]*t[j];
#pragma unroll
    for(int i=0;i<9;i++) a[9+i]+=r[i];
#pragma unroll
    for(int i=0;i<9;i++)
#pragma unroll
      for(int j=i;j<9;j++) a[18 + i*9 - (i*(i-1))/2 + (j-i)] += r[i]*r[j];
  }
#pragma unroll
  for(int i=0;i<63;i++) a[i]=wred(a[i]);
  __shared__ __align__(16) float lds[4][63];
  int wave=threadIdx.x>>6, lane=threadIdx.x&63;
  if(lane==0){
#pragma unroll
    for(int i=0;i<63;i++) lds[wave][i]=a[i];
  }
  __syncthreads();
  int t=threadIdx.x;
  if(t<63) pA[t*gridDim.x + blockIdx.x] = lds[0][t]+lds[1][t]+lds[2][t]+lds[3][t];
}

// ---------------- kA2: reduce moments -> folded BN1 scale/bias; write folded W1f (full 480, looped)
__global__ __launch_bounds__(256) void kA2(const float* __restrict__ pA, int nb,
    const float* __restrict__ kW1, const float* __restrict__ kg, const float* __restrict__ kb,
    const float* __restrict__ qW1, const float* __restrict__ qg, const float* __restrict__ qb,
    const float* __restrict__ vW1, const float* __restrict__ vg, const float* __restrict__ vb,
    float* __restrict__ cst, float* __restrict__ wf, float invN){
  __shared__ __align__(16) float tmp[63][4];
  __shared__ __align__(16) float mom[63];
  __shared__ __align__(16) float sSc[96];
  int t=threadIdx.x;
  if(t<252){
    int f=t>>2, q=t&3;
    int per=nb/4;
    float s=0.f;
    for(int i=0;i<per;i++) s+=pA[f*nb + q*per + i];
    tmp[f][q]=s;
  }
  __syncthreads();
  if(t<63) mom[t]=tmp[t][0]+tmp[t][1]+tmp[t][2]+tmp[t][3];
  __syncthreads();
  if(t<96){
    int net=t>>5, j=t&31;
    const float* W1; const float* g; const float* b; int din, sbase, mbase, obase;
    if(net==0){W1=kW1;g=kg;b=kb;din=3;sbase=0;mbase=3;obase=0;}
    else if(net==1){W1=qW1;g=qg;b=qb;din=9;sbase=9;mbase=18;obase=64;}
    else {W1=vW1;g=vg;b=vb;din=3;sbase=0;mbase=3;obase=128;}
    float mean=0.f, ex2=0.f;
    for(int i=0;i<din;i++){
      float wi=W1[i*32+j];
      mean += mom[sbase+i]*wi;
      int rowb = mbase + i*din - (i*(i-1))/2;
      for(int i2=i;i2<din;i2++){
        float w2=W1[i2*32+j];
        float m=mom[rowb + (i2-i)];
        ex2 += ((i2==i)?1.f:2.f)*wi*w2*m;
      }
    }
    mean*=invN; ex2*=invN;
    float var=ex2-mean*mean;
    float sc=g[j]*rsqrtf(var+EPS);
    float bi=b[j]-mean*sc;
    cst[obase+j]=sc; cst[obase+32+j]=bi;
    sSc[net*32+j]=sc;
  }
  __syncthreads();
  for(int i=threadIdx.x; i<480; i+=256){
    float v;
    if(i<96)       v = kW1[i]      * sSc[i&31];
    else if(i<384) v = qW1[i-96]   * sSc[32+((i-96)&31)];
    else           v = vW1[i-384]  * sSc[64+((i-384)&31)];
    wf[i]=v;
  }
}

// ---------------- kRed: reduce per-block {sum,sumsq} partials -> BN scale/bias
__global__ __launch_bounds__(256) void kRed(const float* __restrict__ part, int nf, int nb,
    const float* __restrict__ g, const float* __restrict__ b, float* __restrict__ cstOut, float invN){
  int f=blockIdx.x;
  float s1=0.f,s2=0.f;
  for(int i=threadIdx.x;i<nb;i+=256){ s1+=part[f*nb+i]; s2+=part[(nf+f)*nb+i]; }
  s1=wred(s1); s2=wred(s2);
  __shared__ __align__(16) float l1[4],l2[4];
  int wave=threadIdx.x>>6;
  if((threadIdx.x&63)==0){l1[wave]=s1;l2[wave]=s2;}
  __syncthreads();
  if(threadIdx.x==0){
    float a=l1[0]+l1[1]+l1[2]+l1[3];
    float c=l2[0]+l2[1]+l2[2]+l2[3];
    float mean=a*invN;
    float var=c*invN-mean*mean;
    float sc=g[f]*rsqrtf(var+EPS);
    float bi=b[f]-mean*sc;
    cstOut[f]=sc; cstOut[nf+f]=bi;
  }
}

// ---------------- kHeavyM: MFMA per-row pipeline -> y1(bf16) + BN-d1 stats
// 4 waves/block, each wave: 16 tiles of 16 rows. cvtpk packing + input prefetch pipeline.
__global__ __launch_bounds__(256) void kHeavyM(
    const float* __restrict__ rot, const float* __restrict__ tra,
    const float* __restrict__ cst, const float* __restrict__ wf,
    const unsigned short* __restrict__ wbf,
    const float* __restrict__ kb2, const float* __restrict__ qb2, const float* __restrict__ vb2,
    unsigned short* __restrict__ y1o, float* __restrict__ pB, int N, int nb)
{
  __shared__ __align__(16) float sW[480];
  __shared__ __align__(16) float pbuf[4][1024];          // per-wave 16x64 f32 (swizzled)
  __shared__ __align__(16) unsigned short ybuf[4][512];  // per-wave 16x32 bf16 (swizzled)
  __shared__ __align__(16) float sStat[4][64];
  for(int i=threadIdx.x;i<480;i+=256) sW[i]=wf[i];
  int wv=threadIdx.x>>6, lane=threadIdx.x&63;
  int c=lane&15, g=lane>>4;

  // resident b-fragments (bf16x8 per lane)
  U8 bK[4],bQ[4],bV[4],bD[2][2];
#pragma unroll
  for(int t=0;t<4;t++){
    bK[t].u = *(const uint4*)(wbf +        (t*16+c)*32 + 8*g);
    bQ[t].u = *(const uint4*)(wbf + 2048 + (t*16+c)*32 + 8*g);
    bV[t].u = *(const uint4*)(wbf + 4096 + (t*16+c)*32 + 8*g);
  }
#pragma unroll
  for(int kc=0;kc<2;kc++)
#pragma unroll
    for(int nt=0;nt<2;nt++)
      bD[kc][nt].u = *(const uint4*)(wbf + 6144 + (nt*16+c)*64 + kc*32 + 8*g);

  // resident biases
  float bk2[4],bq2[4],bv2[4];
#pragma unroll
  for(int t=0;t<4;t++){ bk2[t]=kb2[t*16+c]; bq2[t]=qb2[t*16+c]; bv2[t]=vb2[t*16+c]; }
  float bbk[8],bbq[8],bbv[8];
#pragma unroll
  for(int i=0;i<8;i++){
    bbk[i]=cst[32+8*g+i];
    bbq[i]=cst[96+8*g+i];
    bbv[i]=cst[160+8*g+i];
  }

  float stS0=0.f, stS1=0.f, stQ0=0.f, stQ1=0.f;
  __syncthreads();

  float* pb = pbuf[wv];
  unsigned short* yb = ybuf[wv];
  int tileBase = blockIdx.x*1024 + wv*16;

  // -------- input prefetch pipeline --------
  float t0,t1,t2, rr[9];
  {
    int r0 = tileBase + c;
    int lr = (r0 < N) ? r0 : (N-1);
    t0=tra[lr*3+0]; t1=tra[lr*3+1]; t2=tra[lr*3+2];
#pragma unroll
    for(int i=0;i<9;i++) rr[i]=rot[lr*9+i];
  }

  for(int it=0; it<16; ++it, tileBase += 64){
    if(tileBase >= N) break;             // no barriers inside loop (wave-private LDS)
    int row = tileBase + c;
    bool vrow = row < N;

    // issue next tile's loads early (hidden under this tile's compute)
    float nt0,nt1,nt2, nrr[9];
    {
      int r2 = tileBase + 64 + c;
      int lr2 = (r2 < N) ? r2 : (N-1);
      nt0=tra[lr2*3+0]; nt1=tra[lr2*3+1]; nt2=tra[lr2*3+2];
#pragma unroll
      for(int i=0;i<9;i++) nrr[i]=rot[lr2*9+i];
    }

    // first layers (folded BN1), 8 k-slots per lane
    float hk[8],hq[8],hv[8];
#pragma unroll
    for(int i=0;i<8;i++){ hk[i]=bbk[i]; hq[i]=bbq[i]; hv[i]=bbv[i]; }
#pragma unroll
    for(int i=0;i<3;i++){
      float xi = (i==0)?t0:((i==1)?t1:t2);
#pragma unroll
      for(int j=0;j<8;j++){
        hk[j]+=xi*sW[i*32+8*g+j];
        hv[j]+=xi*sW[384+i*32+8*g+j];
      }
    }
#pragma unroll
    for(int i=0;i<9;i++){
      float xi = rr[i];
#pragma unroll
      for(int j=0;j<8;j++) hq[j]+=xi*sW[96+i*32+8*g+j];
    }
    U8 aK,aQ,aV;
#pragma unroll
    for(int i=0;i<8;i++){ hk[i]=fmaxf(hk[i],0.f); hq[i]=fmaxf(hq[i],0.f); hv[i]=fmaxf(hv[i],0.f); }
    aK.u = make_uint4(cvtpk(hk[0],hk[1]),cvtpk(hk[2],hk[3]),cvtpk(hk[4],hk[5]),cvtpk(hk[6],hk[7]));
    aQ.u = make_uint4(cvtpk(hq[0],hq[1]),cvtpk(hq[2],hq[3]),cvtpk(hq[4],hq[5]),cvtpk(hq[6],hq[7]));
    aV.u = make_uint4(cvtpk(hv[0],hv[1]),cvtpk(hv[2],hv[3]),cvtpk(hv[4],hv[5]),cvtpk(hv[6],hv[7]));

    // k,q GEMMs -> s = (k+kb2)*(q+qb2)   [D layout: row m=4g+rg, col n=16t+c]
    f32x4 z4 = {0.f,0.f,0.f,0.f};
    f32x4 ack[4], acq[4];
#pragma unroll
    for(int t=0;t<4;t++) ack[t]=MFMA16(aK.s, bK[t].s, z4);
#pragma unroll
    for(int t=0;t<4;t++) acq[t]=MFMA16(aQ.s, bQ[t].s, z4);
    f32x4 s4[4];
#pragma unroll
    for(int t=0;t<4;t++)
#pragma unroll
      for(int rg=0;rg<4;rg++) s4[t][rg]=(ack[t][rg]+bk2[t])*(acq[t][rg]+bq2[t]);

    // softmax over n (4 tiles x 16 lanes within group)
    f32x4 mx = s4[0];
#pragma unroll
    for(int t=1;t<4;t++)
#pragma unroll
      for(int rg=0;rg<4;rg++) mx[rg]=fmaxf(mx[rg],s4[t][rg]);
#pragma unroll
    for(int m=8;m>=1;m>>=1)
#pragma unroll
      for(int rg=0;rg<4;rg++) mx[rg]=fmaxf(mx[rg],__shfl_xor(mx[rg],m,64));
    f32x4 zz = z4;
#pragma unroll
    for(int t=0;t<4;t++)
#pragma unroll
      for(int rg=0;rg<4;rg++){ float e=__expf(s4[t][rg]-mx[rg]); s4[t][rg]=e; zz[rg]+=e; }
#pragma unroll
    for(int m=8;m>=1;m>>=1)
#pragma unroll
      for(int rg=0;rg<4;rg++) zz[rg]+=__shfl_xor(zz[rg],m,64);
    f32x4 inv;
#pragma unroll
    for(int rg=0;rg<4;rg++) inv[rg]=1.f/zz[rg];

    // v GEMM, P = e*inv*(v+vb2) -> swizzled LDS
    f32x4 acv[4];
#pragma unroll
    for(int t=0;t<4;t++) acv[t]=MFMA16(aV.s, bV[t].s, z4);
#pragma unroll
    for(int t=0;t<4;t++)
#pragma unroll
      for(int rg=0;rg<4;rg++){
        float P = s4[t][rg]*inv[rg]*(acv[t][rg]+bv2[t]);
        int m = 4*g+rg, n = 16*t+c;
        pb[(m*64 + n) ^ ((m&7)<<3)] = P;
      }

    // y1 = P @ dW1 (a-frags read back from LDS, packed via cvtpk)
    f32x4 acy0=z4, acy1=z4;
#pragma unroll
    for(int kc=0;kc<2;kc++){
      int idx = (c*64 + 32*kc + 8*g) ^ ((c&7)<<3);
      float p0=pb[idx+0], p1=pb[idx+1], p2=pb[idx+2], p3=pb[idx+3];
      float p4=pb[idx+4], p5=pb[idx+5], p6=pb[idx+6], p7=pb[idx+7];
      U8 ap;
      ap.u = make_uint4(cvtpk(p0,p1),cvtpk(p2,p3),cvtpk(p4,p5),cvtpk(p6,p7));
      acy0 = MFMA16(ap.s, bD[kc][0].s, acy0);
      acy1 = MFMA16(ap.s, bD[kc][1].s, acy1);
    }
    // mask invalid rows
#pragma unroll
    for(int rg=0;rg<4;rg++){
      if(tileBase + 4*g + rg >= N){ acy0[rg]=0.f; acy1[rg]=0.f; }
    }
    // stats
#pragma unroll
    for(int rg=0;rg<4;rg++){
      stS0+=acy0[rg]; stQ0+=acy0[rg]*acy0[rg];
      stS1+=acy1[rg]; stQ1+=acy1[rg]*acy1[rg];
    }
    // y1 store via swizzled LDS -> coalesced 16B (one cvtpk per rg)
#pragma unroll
    for(int rg=0;rg<4;rg++){
      int m=4*g+rg;
      unsigned pr = cvtpk(acy0[rg], acy1[rg]);
      yb[(m*32 + c)      ^ ((m&3)<<3)] = (unsigned short)pr;
      yb[(m*32 + 16 + c) ^ ((m&3)<<3)] = (unsigned short)(pr>>16);
    }
    {
      int idx = (c*32 + 8*g) ^ ((c&3)<<3);
      uint4 vv = *(uint4*)&yb[idx];
      if(vrow) *(uint4*)(y1o + (size_t)row*32 + 8*g) = vv;
    }

    // rotate prefetched inputs
    t0=nt0; t1=nt1; t2=nt2;
#pragma unroll
    for(int i=0;i<9;i++) rr[i]=nrr[i];
  }
  // block stats reduction: f = {c, 16+c} sums / sqs
  stS0+=__shfl_xor(stS0,16,64); stS0+=__shfl_xor(stS0,32,64);
  stS1+=__shfl_xor(stS1,16,64); stS1+=__shfl_xor(stS1,32,64);
  stQ0+=__shfl_xor(stQ0,16,64); stQ0+=__shfl_xor(stQ0,32,64);
  stQ1+=__shfl_xor(stQ1,16,64); stQ1+=__shfl_xor(stQ1,32,64);
  if(g==0){
    sStat[wv][c]=stS0; sStat[wv][16+c]=stS1;
    sStat[wv][32+c]=stQ0; sStat[wv][48+c]=stQ1;
  }
  __syncthreads();
  int t=threadIdx.x;
  if(t<64) pB[t*nb + blockIdx.x] = sStat[0][t]+sStat[1][t]+sStat[2][t]+sStat[3][t];
}

// ---------------- kCM: y1(bf16) -> BN-d1 -> ReLU -> dW2 (MFMA) -> y2(bf16) + stats
__global__ __launch_bounds__(256) void kCM(const unsigned short* __restrict__ y1,
    const float* __restrict__ cst, const unsigned short* __restrict__ wbf,
    unsigned short* __restrict__ y2o, float* __restrict__ pC, int N, int nb){
  __shared__ __align__(16) unsigned short ybuf[4][256];  // per-wave 16x16 bf16
  __shared__ __align__(16) float sStat[4][32];
  int wv=threadIdx.x>>6, lane=threadIdx.x&63;
  int c=lane&15, g=lane>>4;
  U8 bD2; bD2.u = *(const uint4*)(wbf + 8192 + c*32 + 8*g);
  float sc[8], bi[8];
#pragma unroll
  for(int i=0;i<8;i++){ sc[i]=cst[192+8*g+i]; bi[i]=cst[224+8*g+i]; }
  float stS=0.f, stQ=0.f;
  unsigned short* yb = ybuf[wv];
  int tileBase = blockIdx.x*1024 + wv*16;
  f32x4 z4 = {0.f,0.f,0.f,0.f};
  for(int it=0; it<16; ++it, tileBase += 64){
    if(tileBase >= N) break;
    int row = tileBase + c;
    bool vrow = row < N;
    int lr = vrow ? row : 0;
    uint4 w = *(const uint4*)(y1 + (size_t)lr*32 + 8*g);
    unsigned wu[4]={w.x,w.y,w.z,w.w};
    float h[8];
#pragma unroll
    for(int j=0;j<4;j++){ h[2*j]=bflo(wu[j]); h[2*j+1]=bfhi(wu[j]); }
#pragma unroll
    for(int i=0;i<8;i++){ float x=h[i]*sc[i]+bi[i]; h[i]=fmaxf(x,0.f); }
    U8 a;
    a.u = make_uint4(cvtpk(h[0],h[1]),cvtpk(h[2],h[3]),cvtpk(h[4],h[5]),cvtpk(h[6],h[7]));
    f32x4 acc = MFMA16(a.s, bD2.s, z4);
#pragma unroll
    for(int rg=0;rg<4;rg++){
      if(tileBase + 4*g + rg >= N) acc[rg]=0.f;
      stS+=acc[rg]; stQ+=acc[rg]*acc[rg];
    }
#pragma unroll
    for(int rg=0;rg<4;rg++){
      int m=4*g+rg;
      yb[(m*16 + c) ^ ((m&3)<<2)] = f2bf(acc[rg]);
    }
    {
      int idx = (c*16 + 4*g) ^ ((c&3)<<2);
      uint2 vv = *(uint2*)&yb[idx];
      if(vrow) *(uint2*)(y2o + (size_t)row*16 + 4*g) = vv;
    }
  }
  stS+=__shfl_xor(stS,16,64); stS+=__shfl_xor(stS,32,64);
  stQ+=__shfl_xor(stQ,16,64); stQ+=__shfl_xor(stQ,32,64);
  if(g==0){ sStat[wv][c]=stS; sStat[wv][16+c]=stQ; }
  __syncthreads();
  int t=threadIdx.x;
  if(t<32) pC[t*nb + blockIdx.x] = sStat[0][t]+sStat[1][t]+sStat[2][t]+sStat[3][t];
}

// ---------------- kD: y2(bf16) -> BN-d2 -> ReLU -> dW3+db3 -> sigmoid -> out
__global__ __launch_bounds__(256) void kD(const unsigned short* __restrict__ y2,
    const float* __restrict__ cst, const float* __restrict__ dW3, const float* __restrict__ db3,
    float* __restrict__ outp, int N){
  int row=blockIdx.x*256+threadIdx.x;
  if(row>=N) return;
  const uint4* src=(const uint4*)(y2+(size_t)row*16);
  uint4 q0=src[0],q1=src[1];
  unsigned int w[8]={q0.x,q0.y,q0.z,q0.w,q1.x,q1.y,q1.z,q1.w};
  float o=db3[0];
#pragma unroll
  for(int kk=0;kk<8;kk++){
    float lo=bflo(w[kk])*cst[256+2*kk]+cst[272+2*kk];
    float hi=bfhi(w[kk])*cst[256+2*kk+1]+cst[272+2*kk+1];
    lo=lo>0.f?lo:0.f; hi=hi>0.f?hi:0.f;
    o+=lo*dW3[2*kk]+hi*dW3[2*kk+1];
  }
  outp[row]=1.f/(1.f+__expf(-o));
}

extern "C" void kernel_launch(void* const* d_in, const int* in_sizes, int n_in,
                              void* d_out, int out_size, void* d_ws, size_t ws_size,
                              hipStream_t stream){
  const float* rot=(const float*)d_in[0];
  const float* tra=(const float*)d_in[1];
  const float* kW1=(const float*)d_in[2];
  const float* kg =(const float*)d_in[3];
  const float* kb =(const float*)d_in[4];
  const float* kW2=(const float*)d_in[5];
  const float* kb2=(const float*)d_in[6];
  const float* qW1=(const float*)d_in[7];
  const float* qg =(const float*)d_in[8];
  const float* qb =(const float*)d_in[9];
  const float* qW2=(const float*)d_in[10];
  const float* qb2=(const float*)d_in[11];
  const float* vW1=(const float*)d_in[12];
  const float* vg =(const float*)d_in[13];
  const float* vb =(const float*)d_in[14];
  const float* vW2=(const float*)d_in[15];
  const float* vb2=(const float*)d_in[16];
  const float* dW1=(const float*)d_in[17];
  const float* dg1=(const float*)d_in[18];
  const float* db1=(const float*)d_in[19];
  const float* dW2=(const float*)d_in[20];
  const float* dg2=(const float*)d_in[21];
  const float* db2=(const float*)d_in[22];
  const float* dW3=(const float*)d_in[23];
  const float* db3=(const float*)d_in[24];

  int N=in_sizes[0]/9;
  int nbH=(N+1023)/1024;

  float* ws=(float*)d_ws;
  float* cst=ws;                         // [0,1024)
  float* wf =ws+1024;                    // [1024,1536) folded W1
  float* pA =ws+1536;                    // 63*1024 -> ends 66048
  float* pB =ws+66048;                   // [64][nbH]
  float* pC =pB+(size_t)64*nbH;          // [32][nbH]
  unsigned short* wbf=(unsigned short*)(pC+(size_t)32*nbH);  // 8704 shorts

  size_t y1off=(size_t)8<<20;            // bytes
  unsigned short* y1=(unsigned short*)((char*)d_ws + y1off);
  unsigned short* y2=(unsigned short*)((char*)d_ws + y1off + (size_t)N*64);
  float invN=1.f/(float)N;
  dim3 B(256);

  kT <<<dim3(1),   B,0,stream>>>(kW2,qW2,vW2,dW1,dW2,wbf);
  kA <<<dim3(1024),B,0,stream>>>(rot,tra,pA,N);
  kA2<<<dim3(1),   B,0,stream>>>(pA,1024,kW1,kg,kb,qW1,qg,qb,vW1,vg,vb,cst,wf,invN);

  kHeavyM<<<dim3(nbH),B,0,stream>>>(rot,tra,cst,wf,wbf,kb2,qb2,vb2,y1,pB,N,nbH);
  kRed<<<dim3(32),B,0,stream>>>(pB,32,nbH,dg1,db1,cst+192,invN);
  kCM<<<dim3(nbH),B,0,stream>>>(y1,cst,wbf,y2,pC,N,nbH);
  kRed<<<dim3(16),B,0,stream>>>(pC,16,nbH,dg2,db2,cst+256,invN);
  kD <<<dim3((N+255)/256),B,0,stream>>>(y2,cst,dW3,db3,(float*)d_out,N);
}